// Round 1
// baseline (119.766 us; speedup 1.0000x reference)
//
#include <hip/hip_runtime.h>

#define BATCH 16384
#define NPTS  500
#define NOBJ  30

// One wave (64 lanes) per batch element; 4 waves per block.
__global__ __launch_bounds__(256) void add_loss_kernel(
    const float* __restrict__ pred_r,   // (B,4)
    const float* __restrict__ pred_t,   // (B,3)
    const float* __restrict__ gt_r,     // (B,4)
    const float* __restrict__ gt_t,     // (B,3)
    const int*   __restrict__ obj_ids,  // (B,)
    const float* __restrict__ points,   // (NOBJ, NPTS, 3)
    float* __restrict__ out)            // scalar
{
    const int wave = threadIdx.x >> 6;   // 0..3
    const int lane = threadIdx.x & 63;
    const int b    = blockIdx.x * 4 + wave;

    float contrib = 0.0f;

    if (b < BATCH) {
        // quaternions are 16B-aligned rows of a (B,4) f32 array
        const float4 qp = ((const float4*)pred_r)[b];
        const float4 qg = ((const float4*)gt_r)[b];

        // quat_to_mat (NO normalization — matches reference exactly)
        // R = [[1-2y2-2z2, 2xy-2wz,   2xz+2wy ],
        //      [2xy+2wz,   1-2x2-2z2, 2yz-2wx ],
        //      [2xz-2wy,   2yz+2wx,   1-2x2-2y2]]
        float pw=qp.x, px=qp.y, py=qp.z, pz=qp.w;
        float gw=qg.x, gx=qg.y, gy=qg.z, gz=qg.w;

        float p00 = 1.f - 2.f*(py*py + pz*pz);
        float p01 = 2.f*(px*py - pw*pz);
        float p02 = 2.f*(px*pz + pw*py);
        float p10 = 2.f*(px*py + pw*pz);
        float p11 = 1.f - 2.f*(px*px + pz*pz);
        float p12 = 2.f*(py*pz - pw*px);
        float p20 = 2.f*(px*pz - pw*py);
        float p21 = 2.f*(py*pz + pw*px);
        float p22 = 1.f - 2.f*(px*px + py*py);

        float g00 = 1.f - 2.f*(gy*gy + gz*gz);
        float g01 = 2.f*(gx*gy - gw*gz);
        float g02 = 2.f*(gx*gz + gw*gy);
        float g10 = 2.f*(gx*gy + gw*gz);
        float g11 = 1.f - 2.f*(gx*gx + gz*gz);
        float g12 = 2.f*(gy*gz - gw*gx);
        float g20 = 2.f*(gx*gz - gw*gy);
        float g21 = 2.f*(gy*gz + gw*gx);
        float g22 = 1.f - 2.f*(gx*gx + gy*gy);

        float d00 = p00-g00, d01 = p01-g01, d02 = p02-g02;
        float d10 = p10-g10, d11 = p11-g11, d12 = p12-g12;
        float d20 = p20-g20, d21 = p21-g21, d22 = p22-g22;

        float tdx = pred_t[3*b+0] - gt_t[3*b+0];
        float tdy = pred_t[3*b+1] - gt_t[3*b+1];
        float tdz = pred_t[3*b+2] - gt_t[3*b+2];

        const int obj = obj_ids[b];
        const float* __restrict__ P = points + (size_t)obj * (NPTS*3);

        float s_add = 0.f, s_rot = 0.f;
        for (int i = lane; i < NPTS; i += 64) {
            float x = P[3*i+0], y = P[3*i+1], z = P[3*i+2];
            float vx = d00*x + d01*y + d02*z;
            float vy = d10*x + d11*y + d12*z;
            float vz = d20*x + d21*y + d22*z;
            s_rot += sqrtf(vx*vx + vy*vy + vz*vz);
            float ax = vx + tdx, ay = vy + tdy, az = vz + tdz;
            s_add += sqrtf(ax*ax + ay*ay + az*az);
        }

        // wave-level butterfly reduce (width 64)
        #pragma unroll
        for (int off = 32; off > 0; off >>= 1) {
            s_add += __shfl_down(s_add, off, 64);
            s_rot += __shfl_down(s_rot, off, 64);
        }

        if (lane == 0) {
            float trans = sqrtf(tdx*tdx + tdy*tdy + tdz*tdz);
            contrib = (s_add + s_rot) * (1.0f / NPTS) + trans;
        }
    }

    __shared__ float red[4];
    if (lane == 0) red[wave] = contrib;
    __syncthreads();
    if (threadIdx.x == 0) {
        float s = red[0] + red[1] + red[2] + red[3];
        atomicAdd(out, s * (1.0f / BATCH));
    }
}

extern "C" void kernel_launch(void* const* d_in, const int* in_sizes, int n_in,
                              void* d_out, int out_size, void* d_ws, size_t ws_size,
                              hipStream_t stream) {
    const float* pred_r  = (const float*)d_in[0];
    const float* pred_t  = (const float*)d_in[1];
    const float* gt_r    = (const float*)d_in[2];
    const float* gt_t    = (const float*)d_in[3];
    const int*   obj_ids = (const int*)d_in[4];
    const float* points  = (const float*)d_in[5];
    float* out = (float*)d_out;

    // d_out is re-poisoned to 0xAA before every replay — zero it on-stream.
    hipMemsetAsync(out, 0, sizeof(float) * out_size, stream);

    const int blocks = (BATCH + 3) / 4;  // 4 batch elements (waves) per block
    add_loss_kernel<<<blocks, 256, 0, stream>>>(
        pred_r, pred_t, gt_r, gt_t, obj_ids, points, out);
}

// Round 2
// 83.511 us; speedup vs baseline: 1.4341x; 1.4341x over previous
//
#include <hip/hip_runtime.h>

#define BATCH 16384
#define NPTS  500
#define NOBJ  30
#define EPW   4   // batch elements per wave
#define WPB   4   // waves per block
// grid = BATCH / (EPW*WPB) = 1024 blocks, 256 threads

__global__ __launch_bounds__(256) void add_loss_kernel(
    const float* __restrict__ pred_r,   // (B,4)
    const float* __restrict__ pred_t,   // (B,3)
    const float* __restrict__ gt_r,     // (B,4)
    const float* __restrict__ gt_t,     // (B,3)
    const int*   __restrict__ obj_ids,  // (B,)
    const float* __restrict__ points,   // (NOBJ, NPTS, 3)
    float* __restrict__ out)            // scalar
{
    const int wave  = threadIdx.x >> 6;
    const int lane  = threadIdx.x & 63;
    const int gwave = blockIdx.x * WPB + wave;
    const int b0    = gwave * EPW;      // 16384 = 1024*16 exactly, no bounds check

    float acc_pts   = 0.0f;  // per-lane partial of sum_e (s_add_e + s_rot_e)
    float acc_trans = 0.0f;  // wave-uniform

    for (int e = 0; e < EPW; ++e) {
        const int b = b0 + e;

        const float4 qp = ((const float4*)pred_r)[b];
        const float4 qg = ((const float4*)gt_r)[b];

        // quat_to_mat (NO normalization — matches reference exactly)
        float pw=qp.x, px=qp.y, py=qp.z, pz=qp.w;
        float gw=qg.x, gx=qg.y, gy=qg.z, gz=qg.w;

        float d00 = (1.f - 2.f*(py*py + pz*pz)) - (1.f - 2.f*(gy*gy + gz*gz));
        float d01 = 2.f*(px*py - pw*pz)         - 2.f*(gx*gy - gw*gz);
        float d02 = 2.f*(px*pz + pw*py)         - 2.f*(gx*gz + gw*gy);
        float d10 = 2.f*(px*py + pw*pz)         - 2.f*(gx*gy + gw*gz);
        float d11 = (1.f - 2.f*(px*px + pz*pz)) - (1.f - 2.f*(gx*gx + gz*gz));
        float d12 = 2.f*(py*pz - pw*px)         - 2.f*(gy*gz - gw*gx);
        float d20 = 2.f*(px*pz - pw*py)         - 2.f*(gx*gz - gw*gy);
        float d21 = 2.f*(py*pz + pw*px)         - 2.f*(gy*gz + gw*gx);
        float d22 = (1.f - 2.f*(px*px + py*py)) - (1.f - 2.f*(gx*gx + gy*gy));

        float tdx = pred_t[3*b+0] - gt_t[3*b+0];
        float tdy = pred_t[3*b+1] - gt_t[3*b+1];
        float tdz = pred_t[3*b+2] - gt_t[3*b+2];

        const int obj = obj_ids[b];
        const float* __restrict__ P = points + (size_t)obj * (NPTS*3);

        float s = 0.0f;
        // 500 = 7*64 + 52: uniform trip count -> full unroll -> all 21 loads
        // issued ahead of the compute chain (ILP latency hiding).
        #pragma unroll
        for (int it = 0; it < 7; ++it) {
            const int i = it*64 + lane;
            float x = P[3*i+0], y = P[3*i+1], z = P[3*i+2];
            float vx = d00*x + d01*y + d02*z;
            float vy = d10*x + d11*y + d12*z;
            float vz = d20*x + d21*y + d22*z;
            s += sqrtf(vx*vx + vy*vy + vz*vz);
            float ax = vx + tdx, ay = vy + tdy, az = vz + tdz;
            s += sqrtf(ax*ax + ay*ay + az*az);
        }
        if (lane < 52) {  // predicated tail, i in [448, 500)
            const int i = 448 + lane;
            float x = P[3*i+0], y = P[3*i+1], z = P[3*i+2];
            float vx = d00*x + d01*y + d02*z;
            float vy = d10*x + d11*y + d12*z;
            float vz = d20*x + d21*y + d22*z;
            s += sqrtf(vx*vx + vy*vy + vz*vz);
            float ax = vx + tdx, ay = vy + tdy, az = vz + tdz;
            s += sqrtf(ax*ax + ay*ay + az*az);
        }

        acc_pts   += s;
        acc_trans += sqrtf(tdx*tdx + tdy*tdy + tdz*tdz);
    }

    // one butterfly per wave (6 shuffles total)
    #pragma unroll
    for (int off = 32; off > 0; off >>= 1)
        acc_pts += __shfl_down(acc_pts, off, 64);

    __shared__ float red[WPB];
    if (lane == 0)
        red[wave] = acc_pts * (1.0f / NPTS) + acc_trans;
    __syncthreads();
    if (threadIdx.x == 0) {
        float sblk = red[0] + red[1] + red[2] + red[3];
        atomicAdd(out, sblk * (1.0f / BATCH));
    }
}

extern "C" void kernel_launch(void* const* d_in, const int* in_sizes, int n_in,
                              void* d_out, int out_size, void* d_ws, size_t ws_size,
                              hipStream_t stream) {
    const float* pred_r  = (const float*)d_in[0];
    const float* pred_t  = (const float*)d_in[1];
    const float* gt_r    = (const float*)d_in[2];
    const float* gt_t    = (const float*)d_in[3];
    const int*   obj_ids = (const int*)d_in[4];
    const float* points  = (const float*)d_in[5];
    float* out = (float*)d_out;

    hipMemsetAsync(out, 0, sizeof(float) * out_size, stream);

    const int blocks = BATCH / (EPW * WPB);  // 1024
    add_loss_kernel<<<blocks, 256, 0, stream>>>(
        pred_r, pred_t, gt_r, gt_t, obj_ids, points, out);
}

// Round 3
// 83.037 us; speedup vs baseline: 1.4423x; 1.0057x over previous
//
#include <hip/hip_runtime.h>

#define BATCH 16384
#define NPTS  500
#define NOBJ  30
#define EPW   4   // batch elements per wave
#define WPB   4   // waves per block
// grid = BATCH / (EPW*WPB) = 1024 blocks, 256 threads

__global__ __launch_bounds__(256) void add_loss_kernel(
    const float* __restrict__ pred_r,   // (B,4)
    const float* __restrict__ pred_t,   // (B,3)
    const float* __restrict__ gt_r,     // (B,4)
    const float* __restrict__ gt_t,     // (B,3)
    const int*   __restrict__ obj_ids,  // (B,)
    const float* __restrict__ points,   // (NOBJ, NPTS, 3)
    float* __restrict__ out)            // scalar
{
    const int wave  = threadIdx.x >> 6;
    const int lane  = threadIdx.x & 63;
    const int gwave = blockIdx.x * WPB + wave;
    const int b0    = gwave * EPW;      // 16384 = 1024*16 exactly

    float acc_pts   = 0.0f;
    float acc_trans = 0.0f;

    for (int e = 0; e < EPW; ++e) {
        const int b = b0 + e;

        const float4 qp = ((const float4*)pred_r)[b];
        const float4 qg = ((const float4*)gt_r)[b];

        // quat_to_mat (NO normalization — matches reference exactly)
        float pw=qp.x, px=qp.y, py=qp.z, pz=qp.w;
        float gw=qg.x, gx=qg.y, gy=qg.z, gz=qg.w;

        float d00 = (1.f - 2.f*(py*py + pz*pz)) - (1.f - 2.f*(gy*gy + gz*gz));
        float d01 = 2.f*(px*py - pw*pz)         - 2.f*(gx*gy - gw*gz);
        float d02 = 2.f*(px*pz + pw*py)         - 2.f*(gx*gz + gw*gy);
        float d10 = 2.f*(px*py + pw*pz)         - 2.f*(gx*gy + gw*gz);
        float d11 = (1.f - 2.f*(px*px + pz*pz)) - (1.f - 2.f*(gx*gx + gz*gz));
        float d12 = 2.f*(py*pz - pw*px)         - 2.f*(gy*gz - gw*gx);
        float d20 = 2.f*(px*pz - pw*py)         - 2.f*(gx*gz - gw*gy);
        float d21 = 2.f*(py*pz + pw*px)         - 2.f*(gy*gz + gw*gx);
        float d22 = (1.f - 2.f*(px*px + py*py)) - (1.f - 2.f*(gx*gx + gy*gy));

        float tdx = pred_t[3*b+0] - gt_t[3*b+0];
        float tdy = pred_t[3*b+1] - gt_t[3*b+1];
        float tdz = pred_t[3*b+2] - gt_t[3*b+2];

        const int obj = obj_ids[b];
        // object row = 1500 floats = 6000 B (divisible by 16 -> float4-aligned)
        const float4* __restrict__ P4 = (const float4*)(points + (size_t)obj * (NPTS*3));

        float s = 0.0f;
        // 500 points = 125 groups of 4 points (12 floats = 3 float4 per group).
        // iter 0: groups 0..63 (all lanes); iter 1: groups 64..124 (lanes 0..60).
        #pragma unroll
        for (int t = 0; t < 2; ++t) {
            const int g = t*64 + lane;
            if (t == 0 || lane < 61) {
                float4 a = P4[3*g+0];
                float4 bq = P4[3*g+1];
                float4 c = P4[3*g+2];
                float fx[4] = {a.x, a.w, bq.z, c.y};
                float fy[4] = {a.y, bq.x, bq.w, c.z};
                float fz[4] = {a.z, bq.y, c.x, c.w};
                #pragma unroll
                for (int j = 0; j < 4; ++j) {
                    float x = fx[j], y = fy[j], z = fz[j];
                    float vx = d00*x + d01*y + d02*z;
                    float vy = d10*x + d11*y + d12*z;
                    float vz = d20*x + d21*y + d22*z;
                    s += sqrtf(vx*vx + vy*vy + vz*vz);
                    float ax = vx + tdx, ay = vy + tdy, az = vz + tdz;
                    s += sqrtf(ax*ax + ay*ay + az*az);
                }
            }
        }

        acc_pts   += s;
        acc_trans += sqrtf(tdx*tdx + tdy*tdy + tdz*tdz);
    }

    // one butterfly per wave
    #pragma unroll
    for (int off = 32; off > 0; off >>= 1)
        acc_pts += __shfl_down(acc_pts, off, 64);

    __shared__ float red[WPB];
    if (lane == 0)
        red[wave] = acc_pts * (1.0f / NPTS) + acc_trans;
    __syncthreads();
    if (threadIdx.x == 0) {
        float sblk = red[0] + red[1] + red[2] + red[3];
        atomicAdd(out, sblk * (1.0f / BATCH));
    }
}

extern "C" void kernel_launch(void* const* d_in, const int* in_sizes, int n_in,
                              void* d_out, int out_size, void* d_ws, size_t ws_size,
                              hipStream_t stream) {
    const float* pred_r  = (const float*)d_in[0];
    const float* pred_t  = (const float*)d_in[1];
    const float* gt_r    = (const float*)d_in[2];
    const float* gt_t    = (const float*)d_in[3];
    const int*   obj_ids = (const int*)d_in[4];
    const float* points  = (const float*)d_in[5];
    float* out = (float*)d_out;

    hipMemsetAsync(out, 0, sizeof(float) * out_size, stream);

    const int blocks = BATCH / (EPW * WPB);  // 1024
    add_loss_kernel<<<blocks, 256, 0, stream>>>(
        pred_r, pred_t, gt_r, gt_t, obj_ids, points, out);
}

// Round 4
// 82.060 us; speedup vs baseline: 1.4595x; 1.0119x over previous
//
#include <hip/hip_runtime.h>

#define BATCH 16384
#define NPTS  500
#define NOBJ  30
#define EPW   4   // batch elements per wave
#define WPB   4   // waves per block
// grid = BATCH / (EPW*WPB) = 1024 blocks, 256 threads

// raw v_sqrt_f32 (1 ULP), no IEEE denormal-fixup sequence
__device__ __forceinline__ float fsqrt(float x) {
    return __builtin_amdgcn_sqrtf(x);
}

__global__ __launch_bounds__(256) void add_loss_kernel(
    const float* __restrict__ pred_r,   // (B,4)
    const float* __restrict__ pred_t,   // (B,3)
    const float* __restrict__ gt_r,     // (B,4)
    const float* __restrict__ gt_t,     // (B,3)
    const int*   __restrict__ obj_ids,  // (B,)
    const float* __restrict__ points,   // (NOBJ, NPTS, 3)
    float* __restrict__ out)            // scalar
{
    const int wave  = threadIdx.x >> 6;
    const int lane  = threadIdx.x & 63;
    const int gwave = blockIdx.x * WPB + wave;
    const int b0    = gwave * EPW;      // 16384 = 1024*16 exactly

    float acc_pts   = 0.0f;
    float acc_trans = 0.0f;

    for (int e = 0; e < EPW; ++e) {
        const int b = b0 + e;

        const float4 qp = ((const float4*)pred_r)[b];
        const float4 qg = ((const float4*)gt_r)[b];

        // D = Rp - Rg from unnormalized quats, computed as paired differences
        float pw=qp.x, px=qp.y, py=qp.z, pz=qp.w;
        float gw=qg.x, gx=qg.y, gy=qg.z, gz=qg.w;

        float d00 = 2.f*((gy*gy + gz*gz) - (py*py + pz*pz));
        float d01 = 2.f*((px*py - pw*pz) - (gx*gy - gw*gz));
        float d02 = 2.f*((px*pz + pw*py) - (gx*gz + gw*gy));
        float d10 = 2.f*((px*py + pw*pz) - (gx*gy + gw*gz));
        float d11 = 2.f*((gx*gx + gz*gz) - (px*px + pz*pz));
        float d12 = 2.f*((py*pz - pw*px) - (gy*gz - gw*gx));
        float d20 = 2.f*((px*pz - pw*py) - (gx*gz - gw*gy));
        float d21 = 2.f*((py*pz + pw*px) - (gy*gz + gw*gx));
        float d22 = 2.f*((gx*gx + gy*gy) - (px*px + py*py));

        float tdx = pred_t[3*b+0] - gt_t[3*b+0];
        float tdy = pred_t[3*b+1] - gt_t[3*b+1];
        float tdz = pred_t[3*b+2] - gt_t[3*b+2];

        const int obj = obj_ids[b];
        // object row = 1500 floats = 6000 B (divisible by 16 -> float4-aligned)
        const float4* __restrict__ P4 = (const float4*)(points + (size_t)obj * (NPTS*3));

        float s = 0.0f;
        // 500 points = 125 groups of 4 points (3 float4 per group).
        #pragma unroll
        for (int t = 0; t < 2; ++t) {
            const int g = t*64 + lane;
            if (t == 0 || lane < 61) {
                float4 a  = P4[3*g+0];
                float4 bq = P4[3*g+1];
                float4 c  = P4[3*g+2];
                float fx[4] = {a.x, a.w, bq.z, c.y};
                float fy[4] = {a.y, bq.x, bq.w, c.z};
                float fz[4] = {a.z, bq.y, c.x, c.w};
                #pragma unroll
                for (int j = 0; j < 4; ++j) {
                    float x = fx[j], y = fy[j], z = fz[j];
                    float vx = d00*x + d01*y + d02*z;
                    float vy = d10*x + d11*y + d12*z;
                    float vz = d20*x + d21*y + d22*z;
                    s += fsqrt(vx*vx + vy*vy + vz*vz);
                    float ax = vx + tdx, ay = vy + tdy, az = vz + tdz;
                    s += fsqrt(ax*ax + ay*ay + az*az);
                }
            }
        }

        acc_pts   += s;
        acc_trans += fsqrt(tdx*tdx + tdy*tdy + tdz*tdz);
    }

    // one butterfly per wave
    #pragma unroll
    for (int off = 32; off > 0; off >>= 1)
        acc_pts += __shfl_down(acc_pts, off, 64);

    __shared__ float red[WPB];
    if (lane == 0)
        red[wave] = acc_pts * (1.0f / NPTS) + acc_trans;
    __syncthreads();
    if (threadIdx.x == 0) {
        float sblk = red[0] + red[1] + red[2] + red[3];
        atomicAdd(out, sblk * (1.0f / BATCH));
    }
}

extern "C" void kernel_launch(void* const* d_in, const int* in_sizes, int n_in,
                              void* d_out, int out_size, void* d_ws, size_t ws_size,
                              hipStream_t stream) {
    const float* pred_r  = (const float*)d_in[0];
    const float* pred_t  = (const float*)d_in[1];
    const float* gt_r    = (const float*)d_in[2];
    const float* gt_t    = (const float*)d_in[3];
    const int*   obj_ids = (const int*)d_in[4];
    const float* points  = (const float*)d_in[5];
    float* out = (float*)d_out;

    hipMemsetAsync(out, 0, sizeof(float) * out_size, stream);

    const int blocks = BATCH / (EPW * WPB);  // 1024
    add_loss_kernel<<<blocks, 256, 0, stream>>>(
        pred_r, pred_t, gt_r, gt_t, obj_ids, points, out);
}